// Round 6
// baseline (6192.408 us; speedup 1.0000x reference)
//
#include <hip/hip_runtime.h>
#include <math.h>

#define B_ 64
#define G_ 640
#define D_ 256
#define H_ 8
#define DH_ 32
#define NBLK 4
#define TPB 512
#define GVL 512           // g's of gv kept in LDS (rest in regs)
#define GVSTR 516         // padded LDS row stride (floats)
#define NEG_INF_F (-1e9f)

__device__ __constant__ float INV_SQRT_DH = 0.17677669529663687f; // 1/sqrt(32)
__device__ __constant__ float INV_SQRT_D  = 0.0625f;              // 1/sqrt(256)

// ---------------------------------------------------------------------------
// K1: graph_embed (mean over G), fixed_ctx = ge @ W_fixed, q0 = fixed_ctx + ge @ W_step
// ---------------------------------------------------------------------------
__global__ __launch_bounds__(256) void precompute_ctx(
    const float* __restrict__ emb, const float* __restrict__ W_fixed,
    const float* __restrict__ W_step, float* __restrict__ fixed_ctx,
    float* __restrict__ q0)
{
  const int b = blockIdx.x, d = threadIdx.x;
  __shared__ float ge[D_];
  const float* eb = emb + (size_t)b * G_ * D_;
  float s = 0.f;
  for (int g = 0; g < G_; ++g) s += eb[(size_t)g * D_ + d];
  ge[d] = s * (1.0f / (float)G_);
  __syncthreads();
  float fc = 0.f, qq = 0.f;
  for (int k = 0; k < D_; ++k) {
    const float gk = ge[k];
    fc = fmaf(gk, W_fixed[k * D_ + d], fc);
    qq = fmaf(gk, W_step[k * D_ + d], qq);
  }
  fixed_ctx[b * D_ + d] = fc;
  q0[b * D_ + d] = fc + qq;
}

// ---------------------------------------------------------------------------
// K0: Bmat [256 x 1024] = [ gk | gv | Wc = W_node3 @ W_out^T | W_step ]
// ---------------------------------------------------------------------------
__global__ __launch_bounds__(256) void build_bmat(
    const float* __restrict__ W_node, const float* __restrict__ W_step,
    const float* __restrict__ W_out, float* __restrict__ Bmat)
{
  const int k = blockIdx.x, t = threadIdx.x;
  __shared__ float wn3[D_];
  wn3[t] = W_node[k * 768 + 512 + t];
  __syncthreads();
  Bmat[k * 1024 + t]       = W_node[k * 768 + t];
  Bmat[k * 1024 + 256 + t] = W_node[k * 768 + 256 + t];
  float acc = 0.f;
  for (int j = 0; j < D_; ++j) acc = fmaf(wn3[j], W_out[t * D_ + j], acc);
  Bmat[k * 1024 + 512 + t] = acc;
  Bmat[k * 1024 + 768 + t] = W_step[k * D_ + t];
}

// ---------------------------------------------------------------------------
// K2: C[40960 x 1024] = emb @ Bmat, scatter to gkT/gv/lk2T/q_all
// ---------------------------------------------------------------------------
__global__ __launch_bounds__(256) void gemm_scatter(
    const float* __restrict__ A, const float* __restrict__ Bm,
    const float* __restrict__ fixed_ctx,
    float* __restrict__ gkT, float* __restrict__ gv,
    float* __restrict__ lk2T, float* __restrict__ q_all)
{
  __shared__ float As[16][132];
  __shared__ float Bs[16][132];
  const int tid = threadIdx.x;
  const int bm = blockIdx.x;   // 320
  const int bn = blockIdx.y;   // 8
  const int tr = tid / 16, tc = tid % 16;
  const int row0 = bm * 128, col0 = bn * 128;
  float acc[8][8];
#pragma unroll
  for (int i = 0; i < 8; ++i)
#pragma unroll
    for (int j = 0; j < 8; ++j) acc[i][j] = 0.f;

  for (int k0 = 0; k0 < D_; k0 += 16) {
#pragma unroll
    for (int s = tid; s < 512; s += 256) {
      const int r = s >> 2, c4 = (s & 3) * 4;
      const float4 v = *(const float4*)&A[(size_t)(row0 + r) * D_ + k0 + c4];
      As[c4 + 0][r] = v.x; As[c4 + 1][r] = v.y;
      As[c4 + 2][r] = v.z; As[c4 + 3][r] = v.w;
    }
#pragma unroll
    for (int s = tid; s < 512; s += 256) {
      const int r = s >> 5, c4 = (s & 31) * 4;
      *(float4*)&Bs[r][c4] = *(const float4*)&Bm[(size_t)(k0 + r) * 1024 + col0 + c4];
    }
    __syncthreads();
#pragma unroll
    for (int kk = 0; kk < 16; ++kk) {
      float a[8], bfr[8];
#pragma unroll
      for (int i = 0; i < 8; ++i) a[i] = As[kk][tr * 8 + i];
#pragma unroll
      for (int j = 0; j < 8; ++j) bfr[j] = Bs[kk][tc * 8 + j];
#pragma unroll
      for (int i = 0; i < 8; ++i)
#pragma unroll
        for (int j = 0; j < 8; ++j) acc[i][j] = fmaf(a[i], bfr[j], acc[i][j]);
    }
    __syncthreads();
  }

#pragma unroll
  for (int i = 0; i < 8; ++i) {
    const int row = row0 + tr * 8 + i;
    const int bb = row / G_;
    const int g = row - bb * G_;
#pragma unroll
    for (int j = 0; j < 8; ++j) {
      const int n = col0 + tc * 8 + j;
      const float v = acc[i][j];
      if (n < 256) {
        const int h = n >> 5, d = n & 31;
        gkT[(((size_t)bb * H_ + h) * DH_ + d) * G_ + g] = v;
      } else if (n < 512) {
        const int m2 = n - 256, h = m2 >> 5, d = m2 & 31;
        gv[(((size_t)bb * H_ + h) * G_ + g) * DH_ + d] = v;
      } else if (n < 768) {
        const int d = n - 512;
        lk2T[((size_t)bb * D_ + d) * G_ + g] = v;
      } else {
        const int d = n - 768;
        q_all[((size_t)(bb * G_ + g)) * D_ + d] = v + fixed_ctx[bb * D_ + d];
      }
    }
  }
}

// ---------------------------------------------------------------------------
// K3: head-split decode, symmetric all-to-all via self-tagged L3 mailboxes.
// 256 blocks = 64 b x 4, 512 threads. Block blk: heads {2blk,2blk+1} for
// phases 2-3; g-quarter [160*blk,160*blk+160) for logits/argmax/output.
// Round 1: exchange heads (64 tagged u64/block). Round 2: exchange
// {max,idx,esum} summaries (2 tagged u64/block). All blocks compute sel/lse
// redundantly in fixed order -> bit-identical, no master serialization.
// ---------------------------------------------------------------------------
__global__ __launch_bounds__(TPB, 2) void step_a2a(
    const float* __restrict__ gkT, const float* __restrict__ gv,
    const float* __restrict__ lk2T, const float* __restrict__ q_all,
    const float* __restrict__ q0, const int* __restrict__ n_steps_p,
    unsigned long long* __restrict__ hm,    // [B][4][64] tagged heads
    unsigned long long* __restrict__ sm,    // [B][4][2]  tagged summaries
    float* __restrict__ out)
{
  const int x = blockIdx.x;
  const int b   = ((x >> 5) << 3) | (x & 7);   // XCD-swizzle heuristic
  const int blk = (x >> 3) & 3;
  const int t = threadIdx.x;
  const int T = *n_steps_p;
  const int h0 = blk * 2;
  const int d0 = blk * 64;      // heads-vector slice owned for phases 2-3
  const int gq0 = blk * 160;    // g-quarter owned for logits/output
  float* out_logp = out;                         // [B][T][G]
  float* out_pi   = out + (size_t)B_ * T * G_;   // [B][T]

  // ---- LDS ----
  __shared__ __align__(16) float gv_lds[2 * DH_ * GVSTR];  // 132,096 B
  __shared__ __align__(16) float attn_s[2 * G_];           // 5,120 B
  __shared__ float heads_s[D_];                            // full 256 after exchange
  __shared__ float lraw_s[160];
  __shared__ float logits_s[160];
  __shared__ int   vis[G_];                                // 2,560 B
  __shared__ float hpart[8][64];
  __shared__ float esum_p[8][2];
  __shared__ float q_s[64];
  __shared__ float redv[3]; __shared__ int redi[3]; __shared__ float reds[3];
  __shared__ unsigned long long stage[8];
  __shared__ int   sel_s;
  __shared__ float lse_s;

  const int lane = t & 63, wave = t >> 6;
  const int qt  = t & 3;        // phase-2 d-quarter
  const int part3 = t >> 6;     // phase-3 g-part (== wave)
  const int hd3 = t & 63;
  const int hh3 = hd3 >> 5, dd3 = hd3 & 31;
  const int col = t & 31;       // phase-4 d-octet-group: d = col*8..col*8+7
  const int row = t >> 5;       // phase-4 g-row 0..15

  // ---- one-time residency loads ----
  float gk_r[10][8];            // (h,g) pair p = k*128 + t/4; quarter qt
#pragma unroll
  for (int k = 0; k < 10; ++k) {
    const int p = k * 128 + (t >> 2);
    const int hh = (p >= G_) ? 1 : 0;
    const int g = p - hh * G_;
    const float* src = gkT + (((size_t)b * H_ + h0 + hh) * DH_ + qt * 8) * G_ + g;
#pragma unroll
    for (int j = 0; j < 8; ++j) gk_r[k][j] = src[(size_t)j * G_];
  }
  float lk_r[10][8];            // g = gq0 + k*16 + row; d = col*8 + j (ALL 256 d)
#pragma unroll
  for (int k = 0; k < 10; ++k) {
    const int g = gq0 + k * 16 + row;
    const float* src = lk2T + ((size_t)b * D_ + col * 8) * G_ + g;
#pragma unroll
    for (int j = 0; j < 8; ++j) lk_r[k][j] = src[(size_t)j * G_];
  }
  for (int idx = t; idx < 2 * GVL * DH_; idx += TPB) {   // coalesced in d
    const int d = idx & 31, g = (idx >> 5) & (GVL - 1), hh = idx >> 14;
    gv_lds[(hh * DH_ + d) * GVSTR + g] =
        gv[(((size_t)b * H_ + h0 + hh) * G_ + g) * DH_ + d];
  }
  float gv_r[16];               // g in [512,640): g = 512 + part3*16 + i, (hh3,dd3)
  {
    const float* src = gv + (((size_t)b * H_ + h0 + hh3) * G_ + GVL + part3 * 16) * DH_ + dd3;
#pragma unroll
    for (int i = 0; i < 16; ++i) gv_r[i] = src[(size_t)i * DH_];
  }

  for (int idx = t; idx < G_; idx += TPB) vis[idx] = 0;
  if (t == 0) sel_s = 0;
  __syncthreads();

  unsigned long long* myhm = hm + (size_t)b * NBLK * 64;
  unsigned long long* mysm = sm + (size_t)b * NBLK * 2;

  for (int step = 0; step < T; ++step) {
    const unsigned tag = (unsigned)(step + 1);

    // ---- phase 1: q slice (this block's 64 components) ----
    const float* qsrc = (step == 0) ? (q0 + (size_t)b * D_)
                                    : (q_all + ((size_t)b * G_ + sel_s) * D_);
    if (t < 64) q_s[t] = qsrc[d0 + t];
    __syncthreads();

    // ---- phase 2: e[hh][g] = exp(qk/sqrt(dh)), masked -> 0 ----
    float qreg[2][8];
#pragma unroll
    for (int hh = 0; hh < 2; ++hh)
#pragma unroll
      for (int j = 0; j < 8; ++j) qreg[hh][j] = q_s[hh * 32 + qt * 8 + j];
#pragma unroll
    for (int k = 0; k < 10; ++k) {
      const int p = k * 128 + (t >> 2);
      const int hh = (p >= G_) ? 1 : 0;
      const int g = p - hh * G_;
      float a = 0.f;
#pragma unroll
      for (int j = 0; j < 8; ++j) a = fmaf(qreg[hh][j], gk_r[k][j], a);
      a += __shfl_xor(a, 1);
      a += __shfl_xor(a, 2);
      if (qt == 0) attn_s[hh * G_ + g] = vis[g] ? 0.f : expf(a * INV_SQRT_DH);
    }
    __syncthreads();

    // ---- phase 3: own heads[64] = sum_g e*gv (8 g-parts) ----
    {
      const float* gvrow = &gv_lds[(hh3 * DH_ + dd3) * GVSTR];
      const float* arow = &attn_s[hh3 * G_];
      float acc = 0.f, es = 0.f;
      const int gA = part3 * 64;
#pragma unroll
      for (int i = 0; i < 16; ++i) {
        const float4 ev = *(const float4*)&arow[gA + i * 4];
        const float4 gvv = *(const float4*)&gvrow[gA + i * 4];
        acc = fmaf(ev.x, gvv.x, acc); acc = fmaf(ev.y, gvv.y, acc);
        acc = fmaf(ev.z, gvv.z, acc); acc = fmaf(ev.w, gvv.w, acc);
        if (dd3 == 0) es += ev.x + ev.y + ev.z + ev.w;
      }
      const int gB = GVL + part3 * 16;
#pragma unroll
      for (int i = 0; i < 16; ++i) {
        const float e = arow[gB + i];
        acc = fmaf(e, gv_r[i], acc);
        if (dd3 == 0) es += e;
      }
      hpart[part3][hd3] = acc;
      if (dd3 == 0) esum_p[part3][hh3] = es;
    }
    __syncthreads();
    if (t < 64) {
      float num = 0.f, den = 0.f;
#pragma unroll
      for (int p = 0; p < 8; ++p) num += hpart[p][t];
#pragma unroll
      for (int p = 0; p < 8; ++p) den += esum_p[p][t >> 5];
      heads_s[d0 + t] = num / den;
    }
    __syncthreads();

    // ---- round 1: all-to-all heads exchange (self-tagged words) ----
    if (t < 64) {
      const unsigned long long w =
          ((unsigned long long)tag << 32) |
          (unsigned long long)__float_as_uint(heads_s[d0 + t]);
      __hip_atomic_store(&myhm[blk * 64 + t], w, __ATOMIC_RELAXED,
                         __HIP_MEMORY_SCOPE_SYSTEM);
    } else if (t < 256) {
      const int rb = (blk + (t >> 6)) & 3;     // remote block 1..3 away
      const int i = t & 63;
      unsigned long long w;
      while ((unsigned)((w = __hip_atomic_load(&myhm[rb * 64 + i], __ATOMIC_RELAXED,
                                               __HIP_MEMORY_SCOPE_SYSTEM)) >> 32) < tag)
        __builtin_amdgcn_s_sleep(1);
      heads_s[rb * 64 + i] = __uint_as_float((unsigned)w);
    }
    __syncthreads();

    // ---- phase 4: logits for own g-quarter (full 256-d dot, resident lk) ----
    float hreg[8];
#pragma unroll
    for (int j = 0; j < 8; ++j) hreg[j] = heads_s[col * 8 + j];
#pragma unroll
    for (int k = 0; k < 10; ++k) {
      float a = 0.f;
#pragma unroll
      for (int j = 0; j < 8; ++j) a = fmaf(hreg[j], lk_r[k][j], a);
      a += __shfl_xor(a, 1);
      a += __shfl_xor(a, 2);
      a += __shfl_xor(a, 4);
      a += __shfl_xor(a, 8);
      a += __shfl_xor(a, 16);
      if (col == 0) lraw_s[k * 16 + row] = a;
    }
    __syncthreads();

    // ---- tanh/mask + local argmax/esum over the 160-g quarter ----
    {
      float lval = -INFINITY, eval = 0.f;
      int gidx = 1 << 30;
      if (t < 160) {
        float lg = 10.0f * tanhf(lraw_s[t] * INV_SQRT_D);
        if (vis[gq0 + t]) lg = NEG_INF_F;
        logits_s[t] = lg;
        lval = lg; gidx = gq0 + t;
        eval = expf(lg - 10.0f);
      }
      if (t < 192) {
        float v = lval; int vi = gidx; float es = eval;
#pragma unroll
        for (int off = 32; off; off >>= 1) {
          const float ov = __shfl_down(v, off);
          const int oi = __shfl_down(vi, off);
          const float oe = __shfl_down(es, off);
          es += oe;
          if (ov > v || (ov == v && oi < vi)) { v = ov; vi = oi; }
        }
        if (lane == 0) { redv[wave] = v; redi[wave] = vi; reds[wave] = es; }
      }
    }
    __syncthreads();

    // ---- round 2: publish summary, poll all 4, combine redundantly ----
    if (t == 0) {
      float mv = redv[0]; int mi = redi[0]; float ss = reds[0];
      for (int w = 1; w < 3; ++w) {
        ss += reds[w];
        if (redv[w] > mv || (redv[w] == mv && redi[w] < mi)) { mv = redv[w]; mi = redi[w]; }
      }
      const unsigned long long w0 =
          ((unsigned long long)((tag << 16) | (unsigned)mi) << 32) |
          (unsigned long long)__float_as_uint(mv);
      const unsigned long long w1 =
          ((unsigned long long)(tag << 16) << 32) |
          (unsigned long long)__float_as_uint(ss);
      __hip_atomic_store(&mysm[blk * 2 + 0], w0, __ATOMIC_RELAXED, __HIP_MEMORY_SCOPE_SYSTEM);
      __hip_atomic_store(&mysm[blk * 2 + 1], w1, __ATOMIC_RELAXED, __HIP_MEMORY_SCOPE_SYSTEM);
    }
    if (t < 8) {
      unsigned long long w;
      while ((unsigned)((w = __hip_atomic_load(&mysm[t], __ATOMIC_RELAXED,
                                               __HIP_MEMORY_SCOPE_SYSTEM)) >> 48) < tag)
        __builtin_amdgcn_s_sleep(1);
      stage[t] = w;
    }
    __syncthreads();
    if (t == 0) {
      float mv = -INFINITY; int mi = 1 << 30; float ss = 0.f;
#pragma unroll
      for (int k = 0; k < NBLK; ++k) {
        const unsigned long long w0 = stage[2 * k], w1 = stage[2 * k + 1];
        const float v = __uint_as_float((unsigned)w0);
        const int vi = (int)((w0 >> 32) & 0xFFFFu);
        ss += __uint_as_float((unsigned)w1);
        if (v > mv || (v == mv && vi < mi)) { mv = v; mi = vi; }
      }
      sel_s = mi;
      lse_s = 10.0f + logf(ss);
      vis[mi] = 1;
      if (blk == 0) __builtin_nontemporal_store((float)mi, &out_pi[(size_t)b * T + step]);
    }
    __syncthreads();

    // ---- output: own g-quarter ----
    if (t < 160)
      __builtin_nontemporal_store(logits_s[t] - lse_s,
          &out_logp[((size_t)b * T + step) * G_ + gq0 + t]);
  }
}

// ---------------------------------------------------------------------------
extern "C" void kernel_launch(void* const* d_in, const int* in_sizes, int n_in,
                              void* d_out, int out_size, void* d_ws, size_t ws_size,
                              hipStream_t stream)
{
  const float* emb     = (const float*)d_in[0];
  const float* W_node  = (const float*)d_in[1];
  const float* W_fixed = (const float*)d_in[2];
  const float* W_step  = (const float*)d_in[3];
  const float* W_out   = (const float*)d_in[4];
  const int*   n_steps = (const int*)d_in[5];

  float* ws = (float*)d_ws;
  float* fixed_ctx = ws;
  float* q0        = fixed_ctx + B_ * D_;
  float* Bmat      = q0 + B_ * D_;
  float* gkT       = Bmat + D_ * 1024;
  float* gv        = gkT + (size_t)B_ * D_ * G_;
  float* lk2T      = gv + (size_t)B_ * D_ * G_;
  float* q_all     = lk2T + (size_t)B_ * D_ * G_;
  unsigned long long* hm = (unsigned long long*)(q_all + (size_t)B_ * G_ * D_);
  unsigned long long* sm = hm + (size_t)B_ * NBLK * 64;

  // zero mailboxes (harness re-poisons ws with 0xAA -> would fake tags)
  hipMemsetAsync(hm, 0, (size_t)(B_ * NBLK * 64 + B_ * NBLK * 2) * sizeof(unsigned long long), stream);
  precompute_ctx<<<B_, 256, 0, stream>>>(emb, W_fixed, W_step, fixed_ctx, q0);
  build_bmat<<<D_, 256, 0, stream>>>(W_node, W_step, W_out, Bmat);
  gemm_scatter<<<dim3(320, 8), 256, 0, stream>>>(emb, Bmat, fixed_ctx,
                                                 gkT, gv, lk2T, q_all);
  step_a2a<<<B_ * NBLK, TPB, 0, stream>>>(gkT, gv, lk2T, q_all, q0, n_steps,
                                          hm, sm, (float*)d_out);
}